// Round 6
// baseline (162.413 us; speedup 1.0000x reference)
//
#include <hip/hip_runtime.h>
#include <math.h>

#define EPS 1e-6f
#define JPW 8    // j per block (uniform loop)

struct F3 { float x, y, z; };
__device__ inline F3 sub3(F3 a, F3 b){return {a.x-b.x,a.y-b.y,a.z-b.z};}
__device__ inline float dot3(F3 a, F3 b){return a.x*b.x+a.y*b.y+a.z*b.z;}
__device__ inline F3 scale3(F3 a,float s){return {a.x*s,a.y*s,a.z*s};}
__device__ inline F3 cross3(F3 a,F3 b){return {a.y*b.z-a.z*b.y, a.z*b.x-a.x*b.z, a.x*b.y-a.y*b.x};}
__device__ inline F3 norm3(F3 v){float s=dot3(v,v);float inv=1.f/sqrtf(fmaxf(s,EPS));return scale3(v,inv);}

__device__ inline void make_frame(const float* __restrict__ base, float R[9], F3& ca) {
    F3 n = {base[0], base[1], base[2]};
    ca   = {base[3], base[4], base[5]};
    F3 c = {base[6], base[7], base[8]};
    F3 e1 = norm3(sub3(c, ca));
    F3 v2 = sub3(n, ca);
    float d = dot3(e1, v2);
    F3 e2 = norm3({v2.x - d*e1.x, v2.y - d*e1.y, v2.z - d*e1.z});
    F3 e3 = cross3(e1, e2);
    R[0]=e1.x; R[1]=e1.y; R[2]=e1.z;
    R[3]=e2.x; R[4]=e2.y; R[5]=e2.z;
    R[6]=e3.x; R[7]=e3.y; R[8]=e3.z;
}

// ---------------- prep: frames -> fused M,c per (l,i); packed; CA arrays; zero accums ----
__global__ __launch_bounds__(256) void prep_kernel(
    const float* __restrict__ pred, const float* __restrict__ gt,
    const float* __restrict__ atom_mask, const int* __restrict__ batch,
    const int* __restrict__ chain,
    float* __restrict__ Mc, int* __restrict__ packed,
    float* __restrict__ gtca, float* __restrict__ predca,
    float* __restrict__ lddt_s, float* __restrict__ lddt_c,
    float* __restrict__ acc, unsigned int* __restrict__ counter,
    int L, int N, int A)
{
    int idx = blockIdx.x * blockDim.x + threadIdx.x;
    if (idx == 0) { for (int k = 0; k < 8; k++) acc[k] = 0.f; *counter = 0u; }
    if (idx >= L * N) return;
    int l = idx / N, i = idx - l * N;

    float Rg[9]; F3 cag;
    make_frame(gt + (size_t)i * A * 3, Rg, cag);
    float Rp[9]; F3 cap;
    make_frame(pred + ((size_t)l * N + i) * A * 3, Rp, cap);

    // M[d][e] = sum_k Rp[k*3+d] * Rg[k*3+e]  (fused: |Rp^T u - Rg^T v| = |u - M v - c|)
    float m[9];
    #pragma unroll
    for (int d = 0; d < 3; d++)
        #pragma unroll
        for (int e = 0; e < 3; e++)
            m[d*3+e] = Rp[0*3+d]*Rg[0*3+e] + Rp[1*3+d]*Rg[1*3+e] + Rp[2*3+d]*Rg[2*3+e];
    float c0 = cap.x - (m[0]*cag.x + m[1]*cag.y + m[2]*cag.z);
    float c1 = cap.y - (m[3]*cag.x + m[4]*cag.y + m[5]*cag.z);
    float c2 = cap.z - (m[6]*cag.x + m[7]*cag.y + m[8]*cag.z);

    float* o = Mc + (size_t)idx * 12;
    #pragma unroll
    for (int k = 0; k < 9; k++) o[k] = m[k];
    o[9] = c0; o[10] = c1; o[11] = c2;

    if (l == 0) {
        unsigned mm = 0;
        for (int a = 0; a < A; a++)
            if (atom_mask[(size_t)i * A + a] > 0.f) mm |= (1u << a);
        packed[i] = (int)(mm | ((unsigned)batch[i] << 16) | ((unsigned)chain[i] << 24));
        gtca[i*3] = cag.x; gtca[i*3+1] = cag.y; gtca[i*3+2] = cag.z;
        lddt_s[i] = 0.f; lddt_c[i] = 0.f;
    }
    if (l == L - 1) { predca[i*3] = cap.x; predca[i*3+1] = cap.y; predca[i*3+2] = cap.z; }
}

// ---------------- mega (transposed): lane owns i, j uniform per iteration ----
// Rows pred[l,j] / gt[j] are uniform-address -> scalar loads; no LDS in hot loop.
__global__ __launch_bounds__(256) void fape_mega(
    const float* __restrict__ pred, const float* __restrict__ gt,
    const float* __restrict__ Mc, const int* __restrict__ packed,
    const float* __restrict__ gtca, const float* __restrict__ predca,
    float* __restrict__ acc,
    float* __restrict__ lddt_s, float* __restrict__ lddt_c,
    unsigned int* __restrict__ counter,
    float* __restrict__ out, float* __restrict__ out_final,
    float* __restrict__ out_rot, float* __restrict__ out_lddt,
    int L, int N, int gridTotal)
{
    __shared__ float red[4][4];
    __shared__ float redf[4];
    __shared__ int flag;

    int t = threadIdx.x;
    int lane = t & 63, wave = t >> 6;
    int it = blockIdx.x, js = blockIdx.y, l = blockIdx.z;
    int i = it * 256 + t;          // lane-owned i
    bool last = (l == L - 1);

    int pki = packed[i];
    int mi = pki & 0xFFFF;
    int bi = (pki >> 16) & 0xFF, ci = (pki >> 24) & 0xFF;

    const float4* mcp = (const float4*)(Mc + ((size_t)l * N + i) * 12);
    float4 q0 = mcp[0], q1 = mcp[1], q2 = mcp[2];
    float m00 = q0.x, m01 = q0.y, m02 = q0.z;
    float m10 = q0.w, m11 = q1.x, m12 = q1.y;
    float m20 = q1.z, m21 = q1.w, m22 = q2.x;
    float c0 = q2.y, c1 = q2.z, c2 = q2.w;

    float gix = 0.f, giy = 0.f, giz = 0.f, pix = 0.f, piy = 0.f, piz = 0.f;
    if (last) {
        gix = gtca[i*3]; giy = gtca[i*3+1]; giz = gtca[i*3+2];
        pix = predca[i*3]; piy = predca[i*3+1]; piz = predca[i*3+2];
    }

    float s_same = 0.f, s_other = 0.f, c_same = 0.f, c_other = 0.f;
    float ls = 0.f, lc = 0.f;

    int j0 = js * JPW;
    for (int jj = 0; jj < JPW; jj++) {
        int j = j0 + jj;                      // uniform
        int pkj = packed[j];                  // scalar load
        int mjs = pkj & 0xFFFF;
        int bj  = (pkj >> 16) & 0xFF, cj = (pkj >> 24) & 0xFF;
        const float* __restrict__ xr = pred + ((size_t)l * N + j) * 42;  // uniform row
        const float* __restrict__ yr = gt + (size_t)j * 42;              // uniform row

        int mj = mi & mjs;
        bool pm2 = (bi == bj) && (mj != 0);
        float fv = 0.f;
        if (__any(pm2)) {
            float num = 0.f;
            #pragma unroll
            for (int a = 0; a < 14; a++) {
                float y0 = yr[a*3], y1 = yr[a*3+1], y2 = yr[a*3+2];
                float d0 = xr[a*3]   - (m00*y0 + m01*y1 + m02*y2 + c0);
                float d1 = xr[a*3+1] - (m10*y0 + m11*y1 + m12*y2 + c1);
                float d2 = xr[a*3+2] - (m20*y0 + m21*y1 + m22*y2 + c2);
                float s = d0*d0 + d1*d1 + d2*d2;
                num += (float)((mj >> a) & 1) * sqrtf(fmaxf(s, EPS));
            }
            fv = pm2 ? num / (float)__popc((unsigned)mj) : 0.f;
        }
        if (last) out_final[(size_t)i * N + j] = fv;   // scattered column write; L2 merges
        if (i == j) {
            atomicAdd(&acc[2 * L + 2 + l], fv);        // rotamer diag sum
            if (last) out_rot[i] = fv;
        }
        if (pm2) {
            float cl = fminf(fv, 10.f);
            if (ci == cj) { s_same += cl;  c_same += 1.f; }
            else          { s_other += cl; c_other += 1.f; }
        }
        if (last) {
            bool ok = (mi != 0) && (mjs != 0) && (i != j);
            if (__any(ok)) {
                float gjx = gtca[j*3], gjy = gtca[j*3+1], gjz = gtca[j*3+2];   // uniform
                float dx = gix - gjx, dy = giy - gjy, dz = giz - gjz;
                float gd = sqrtf(fmaxf(dx*dx + dy*dy + dz*dz, EPS));
                if (ok && gd < 15.f) {
                    float pjx = predca[j*3], pjy = predca[j*3+1], pjz = predca[j*3+2];
                    float ex = pix - pjx, ey = piy - pjy, ez = piz - pjz;
                    float pd = sqrtf(fmaxf(ex*ex + ey*ey + ez*ez, EPS));
                    float de = fabsf(gd - pd);
                    ls += ((de < 0.5f ? 1.f : 0.f) + (de < 1.f ? 1.f : 0.f) +
                           (de < 2.f ? 1.f : 0.f) + (de < 4.f ? 1.f : 0.f)) * 0.25f;
                    lc += 1.f;
                }
            }
        }
    }

    if (last) {   // per-lane lddt partial for this j-range
        atomicAdd(&lddt_s[i], ls);
        atomicAdd(&lddt_c[i], lc);
    }

    // ---- block reduce 4 accumulators -> global atomics ----
    for (int o = 32; o > 0; o >>= 1) {
        s_same  += __shfl_down(s_same, o, 64);
        s_other += __shfl_down(s_other, o, 64);
        c_same  += __shfl_down(c_same, o, 64);
        c_other += __shfl_down(c_other, o, 64);
    }
    if (lane == 0) {
        red[wave][0] = s_same; red[wave][1] = s_other;
        red[wave][2] = c_same; red[wave][3] = c_other;
    }
    __syncthreads();
    if (t == 0) {
        float ss = 0, so = 0, cs = 0, co = 0;
        for (int w = 0; w < 4; w++) {
            ss += red[w][0]; so += red[w][1]; cs += red[w][2]; co += red[w][3];
        }
        atomicAdd(&acc[l], ss);
        atomicAdd(&acc[L + l], so);
        if (l == 0) {
            atomicAdd(&acc[2 * L], cs);
            atomicAdd(&acc[2 * L + 1], co);
        }
    }

    // ---- ticket: last block finalizes ----
    __threadfence();
    if (t == 0) {
        unsigned tk = atomicAdd(counter, 1u);
        flag = (tk == (unsigned)(gridTotal - 1)) ? 1 : 0;
    }
    __syncthreads();
    if (flag) {
        __threadfence();
        for (int i2 = t; i2 < N; i2 += 256)
            out_lddt[i2] = lddt_s[i2] / fmaxf(lddt_c[i2], 1e-6f);
        float nr = 0.f;
        for (int i2 = t; i2 < N; i2 += 256)
            nr += ((packed[i2] & 0xFFFF) != 0) ? 1.f : 0.f;
        for (int o = 32; o > 0; o >>= 1) nr += __shfl_down(nr, o, 64);
        __syncthreads();
        if (lane == 0) redf[wave] = nr;
        __syncthreads();
        if (t == 0) {
            float n_res = redf[0] + redf[1] + redf[2] + redf[3];
            float cs = fmaxf(acc[2 * L], 1e-6f);
            float co = fmaxf(acc[2 * L + 1], 1e-6f);
            float nrm = fmaxf(n_res, 1e-6f);
            for (int l2 = 0; l2 < L; l2++) {
                out[l2]     = acc[l2] / cs / 10.f + acc[L + l2] / co / 10.f;
                out[L + l2] = acc[2 * L + 2 + l2] / nrm;
            }
        }
    }
}

extern "C" void kernel_launch(void* const* d_in, const int* in_sizes, int n_in,
                              void* d_out, int out_size, void* d_ws, size_t ws_size,
                              hipStream_t stream)
{
    const float* pred      = (const float*)d_in[0];
    const float* gt        = (const float*)d_in[1];
    const float* atom_mask = (const float*)d_in[2];
    const int*   batch     = (const int*)d_in[3];
    const int*   chain     = (const int*)d_in[4];

    int N = in_sizes[3];
    int A = in_sizes[2] / N;
    int L = in_sizes[0] / (N * A * 3);

    float* out = (float*)d_out;
    float* out_final = out + 2 * L;
    float* out_rot   = out_final + (size_t)N * N;
    float* out_lddt  = out_rot + N;

    float* ws = (float*)d_ws;
    float* Mc      = ws;                                  // L*N*12
    float* gtca    = Mc + (size_t)L * N * 12;             // N*3
    float* predca  = gtca + (size_t)N * 3;                // N*3
    float* lddt_s  = predca + (size_t)N * 3;              // N
    float* lddt_c  = lddt_s + N;                          // N
    float* acc     = lddt_c + N;                          // 8
    unsigned int* counter = (unsigned int*)(acc + 8);     // 1
    int* packed    = (int*)(counter + 1);                 // N

    int totalP = L * N;
    prep_kernel<<<(totalP + 255) / 256, 256, 0, stream>>>(
        pred, gt, atom_mask, batch, chain,
        Mc, packed, gtca, predca, lddt_s, lddt_c, acc, counter, L, N, A);

    int IT = N / 256;         // 3
    int JS = N / JPW;         // 96
    dim3 grid(IT, JS, L);     // 576 blocks
    int gridTotal = IT * JS * L;
    fape_mega<<<grid, 256, 0, stream>>>(
        pred, gt, Mc, packed, gtca, predca,
        acc, lddt_s, lddt_c, counter,
        out, out_final, out_rot, out_lddt, L, N, gridTotal);
}

// Round 7
// 97.975 us; speedup vs baseline: 1.6577x; 1.6577x over previous
//
#include <hip/hip_runtime.h>
#include <math.h>

#define EPS 1e-6f
#define IPB 2    // i per block

struct F3 { float x, y, z; };
__device__ inline F3 sub3(F3 a, F3 b){return {a.x-b.x,a.y-b.y,a.z-b.z};}
__device__ inline float dot3(F3 a, F3 b){return a.x*b.x+a.y*b.y+a.z*b.z;}
__device__ inline F3 scale3(F3 a,float s){return {a.x*s,a.y*s,a.z*s};}
__device__ inline F3 cross3(F3 a,F3 b){return {a.y*b.z-a.z*b.y, a.z*b.x-a.x*b.z, a.x*b.y-a.y*b.x};}
__device__ inline F3 norm3(F3 v){float s=dot3(v,v);float inv=1.f/sqrtf(fmaxf(s,EPS));return scale3(v,inv);}

__device__ inline void make_frame(const float* __restrict__ base, float R[9], F3& ca) {
    F3 n = {base[0], base[1], base[2]};
    ca   = {base[3], base[4], base[5]};
    F3 c = {base[6], base[7], base[8]};
    F3 e1 = norm3(sub3(c, ca));
    F3 v2 = sub3(n, ca);
    float d = dot3(e1, v2);
    F3 e2 = norm3({v2.x - d*e1.x, v2.y - d*e1.y, v2.z - d*e1.z});
    F3 e3 = cross3(e1, e2);
    R[0]=e1.x; R[1]=e1.y; R[2]=e1.z;
    R[3]=e2.x; R[4]=e2.y; R[5]=e2.z;
    R[6]=e3.x; R[7]=e3.y; R[8]=e3.z;
}

// ---------------- prep: fused M,c per (l,i); packed; CA arrays ----------------
__global__ __launch_bounds__(256) void prep_kernel(
    const float* __restrict__ pred, const float* __restrict__ gt,
    const float* __restrict__ atom_mask, const int* __restrict__ batch,
    const int* __restrict__ chain,
    float* __restrict__ Mc, int* __restrict__ packed,
    float* __restrict__ gtca, float* __restrict__ predca,
    int L, int N, int A)
{
    int idx = blockIdx.x * blockDim.x + threadIdx.x;
    if (idx >= L * N) return;
    int l = idx / N, i = idx - l * N;

    float Rg[9]; F3 cag;
    make_frame(gt + (size_t)i * A * 3, Rg, cag);
    float Rp[9]; F3 cap;
    make_frame(pred + ((size_t)l * N + i) * A * 3, Rp, cap);

    // |Rp^T(x-tp) - Rg^T(y-tg)| == |x - (M y + c)|, M = Rp Rg^T, c = tp - M tg
    float m[9];
    #pragma unroll
    for (int d = 0; d < 3; d++)
        #pragma unroll
        for (int e = 0; e < 3; e++)
            m[d*3+e] = Rp[0*3+d]*Rg[0*3+e] + Rp[1*3+d]*Rg[1*3+e] + Rp[2*3+d]*Rg[2*3+e];
    float c0 = cap.x - (m[0]*cag.x + m[1]*cag.y + m[2]*cag.z);
    float c1 = cap.y - (m[3]*cag.x + m[4]*cag.y + m[5]*cag.z);
    float c2 = cap.z - (m[6]*cag.x + m[7]*cag.y + m[8]*cag.z);

    float* o = Mc + (size_t)idx * 12;
    #pragma unroll
    for (int k = 0; k < 9; k++) o[k] = m[k];
    o[9] = c0; o[10] = c1; o[11] = c2;

    if (l == 0) {
        unsigned mm = 0;
        for (int a = 0; a < A; a++)
            if (atom_mask[(size_t)i * A + a] > 0.f) mm |= (1u << a);
        packed[i] = (int)(mm | ((unsigned)batch[i] << 16) | ((unsigned)chain[i] << 24));
        gtca[i*3] = cag.x; gtca[i*3+1] = cag.y; gtca[i*3+2] = cag.z;
    }
    if (l == L - 1) { predca[i*3] = cap.x; predca[i*3+1] = cap.y; predca[i*3+2] = cap.z; }
}

// ---------------- fape: block = (l, i-pair), lanes stride j. NO global atomics. ----
// Per-block partials -> plain stores to part[]; lddt block-local (block owns full row i).
__global__ __launch_bounds__(256) void fape_kernel(
    const float* __restrict__ pred, const float* __restrict__ gt,
    const float* __restrict__ Mc, const int* __restrict__ packed,
    const float* __restrict__ gtca, const float* __restrict__ predca,
    float* __restrict__ part,
    float* __restrict__ out_final, float* __restrict__ out_rot,
    float* __restrict__ out_lddt,
    int L, int N)
{
    int t = threadIdx.x;
    int ib = blockIdx.x, l = blockIdx.y;
    int i0 = ib * IPB;
    int i1 = i0 + 1;
    bool last = (l == L - 1);

    // block-uniform -> scalar loads
    const float* __restrict__ mcp = Mc + ((size_t)l * N + i0) * 12;
    float A00=mcp[0],A01=mcp[1],A02=mcp[2],A10=mcp[3],A11=mcp[4],A12=mcp[5],
          A20=mcp[6],A21=mcp[7],A22=mcp[8],Ac0=mcp[9],Ac1=mcp[10],Ac2=mcp[11];
    float B00=mcp[12],B01=mcp[13],B02=mcp[14],B10=mcp[15],B11=mcp[16],B12=mcp[17],
          B20=mcp[18],B21=mcp[19],B22=mcp[20],Bc0=mcp[21],Bc1=mcp[22],Bc2=mcp[23];
    int pk0 = packed[i0], pk1 = packed[i1];
    int msk0 = pk0 & 0xFFFF, bat0 = (pk0 >> 16) & 0xFF, ch0 = (pk0 >> 24) & 0xFF;
    int msk1 = pk1 & 0xFFFF, bat1 = (pk1 >> 16) & 0xFF, ch1 = (pk1 >> 24) & 0xFF;

    float g0x=0,g0y=0,g0z=0,p0x=0,p0y=0,p0z=0;
    float g1x=0,g1y=0,g1z=0,p1x=0,p1y=0,p1z=0;
    if (last) {
        g0x=gtca[i0*3]; g0y=gtca[i0*3+1]; g0z=gtca[i0*3+2];
        p0x=predca[i0*3]; p0y=predca[i0*3+1]; p0z=predca[i0*3+2];
        g1x=gtca[i1*3]; g1y=gtca[i1*3+1]; g1z=gtca[i1*3+2];
        p1x=predca[i1*3]; p1y=predca[i1*3+1]; p1z=predca[i1*3+2];
    }

    float a_ss=0.f, a_so=0.f, a_cs=0.f, a_co=0.f, a_rot=0.f;
    float ls0=0.f, lc0=0.f, ls1=0.f, lc1=0.f;

    for (int j = t; j < N; j += 256) {
        int pkj = packed[j];
        int mskj = pkj & 0xFFFF;
        int bj = (pkj >> 16) & 0xFF, cj = (pkj >> 24) & 0xFF;
        const float2* __restrict__ xr = (const float2*)(pred + ((size_t)l * N + j) * 42);
        const float2* __restrict__ yr = (const float2*)(gt + (size_t)j * 42);

        int mj0 = msk0 & mskj, mj1 = msk1 & mskj;
        bool pm0 = (bj == bat0) && (mj0 != 0);
        bool pm1 = (bj == bat1) && (mj1 != 0);
        float num0 = 0.f, num1 = 0.f;
        float cax=0,cay=0,caz=0, cgx=0,cgy=0,cgz=0;   // CA (atom 1) of row j

        if (__any(pm0 || pm1)) {
            #pragma unroll
            for (int g = 0; g < 7; g++) {
                float2 xa = xr[3*g], xb = xr[3*g+1], xc = xr[3*g+2];
                float2 ya = yr[3*g], yb = yr[3*g+1], yc = yr[3*g+2];
                // atom 2g: x=(xa.x,xa.y,xb.x), y=(ya.x,ya.y,yb.x)
                {
                    float Y0=ya.x, Y1=ya.y, Y2=yb.x;
                    float X0=xa.x, X1=xa.y, X2=xb.x;
                    float d0 = X0 - (A00*Y0 + A01*Y1 + A02*Y2 + Ac0);
                    float d1 = X1 - (A10*Y0 + A11*Y1 + A12*Y2 + Ac1);
                    float d2 = X2 - (A20*Y0 + A21*Y1 + A22*Y2 + Ac2);
                    num0 += (float)((mj0 >> (2*g)) & 1) * sqrtf(fmaxf(d0*d0+d1*d1+d2*d2, EPS));
                    float e0 = X0 - (B00*Y0 + B01*Y1 + B02*Y2 + Bc0);
                    float e1 = X1 - (B10*Y0 + B11*Y1 + B12*Y2 + Bc1);
                    float e2 = X2 - (B20*Y0 + B21*Y1 + B22*Y2 + Bc2);
                    num1 += (float)((mj1 >> (2*g)) & 1) * sqrtf(fmaxf(e0*e0+e1*e1+e2*e2, EPS));
                }
                // atom 2g+1: x=(xb.y,xc.x,xc.y), y=(yb.y,yc.x,yc.y)
                {
                    float Y0=yb.y, Y1=yc.x, Y2=yc.y;
                    float X0=xb.y, X1=xc.x, X2=xc.y;
                    if (g == 0) { cax=X0; cay=X1; caz=X2; cgx=Y0; cgy=Y1; cgz=Y2; }
                    float d0 = X0 - (A00*Y0 + A01*Y1 + A02*Y2 + Ac0);
                    float d1 = X1 - (A10*Y0 + A11*Y1 + A12*Y2 + Ac1);
                    float d2 = X2 - (A20*Y0 + A21*Y1 + A22*Y2 + Ac2);
                    num0 += (float)((mj0 >> (2*g+1)) & 1) * sqrtf(fmaxf(d0*d0+d1*d1+d2*d2, EPS));
                    float e0 = X0 - (B00*Y0 + B01*Y1 + B02*Y2 + Bc0);
                    float e1 = X1 - (B10*Y0 + B11*Y1 + B12*Y2 + Bc1);
                    float e2 = X2 - (B20*Y0 + B21*Y1 + B22*Y2 + Bc2);
                    num1 += (float)((mj1 >> (2*g+1)) & 1) * sqrtf(fmaxf(e0*e0+e1*e1+e2*e2, EPS));
                }
            }
        } else if (last) {
            float2 xb = xr[1], xc = xr[2], yb = yr[1], yc = yr[2];
            cax=xb.y; cay=xc.x; caz=xc.y; cgx=yb.y; cgy=yc.x; cgz=yc.y;
        }

        float fv0 = pm0 ? num0 / (float)__popc((unsigned)mj0) : 0.f;
        float fv1 = pm1 ? num1 / (float)__popc((unsigned)mj1) : 0.f;

        if (last) {
            out_final[(size_t)i0 * N + j] = fv0;   // coalesced
            out_final[(size_t)i1 * N + j] = fv1;
            if (j == i0) out_rot[i0] = fv0;
            if (j == i1) out_rot[i1] = fv1;
        }
        if (j == i0) a_rot += fv0;
        if (j == i1) a_rot += fv1;
        if (pm0) {
            float cl = fminf(fv0, 10.f);
            if (ch0 == cj) { a_ss += cl; a_cs += 1.f; } else { a_so += cl; a_co += 1.f; }
        }
        if (pm1) {
            float cl = fminf(fv1, 10.f);
            if (ch1 == cj) { a_ss += cl; a_cs += 1.f; } else { a_so += cl; a_co += 1.f; }
        }
        if (last) {
            bool ok0 = (msk0 != 0) && (mskj != 0) && (j != i0);
            bool ok1 = (msk1 != 0) && (mskj != 0) && (j != i1);
            if (ok0) {
                float dx=g0x-cgx, dy=g0y-cgy, dz=g0z-cgz;
                float gd = sqrtf(fmaxf(dx*dx+dy*dy+dz*dz, EPS));
                if (gd < 15.f) {
                    float ex=p0x-cax, ey=p0y-cay, ez=p0z-caz;
                    float pd = sqrtf(fmaxf(ex*ex+ey*ey+ez*ez, EPS));
                    float de = fabsf(gd - pd);
                    ls0 += ((de<0.5f?1.f:0.f)+(de<1.f?1.f:0.f)+(de<2.f?1.f:0.f)+(de<4.f?1.f:0.f))*0.25f;
                    lc0 += 1.f;
                }
            }
            if (ok1) {
                float dx=g1x-cgx, dy=g1y-cgy, dz=g1z-cgz;
                float gd = sqrtf(fmaxf(dx*dx+dy*dy+dz*dz, EPS));
                if (gd < 15.f) {
                    float ex=p1x-cax, ey=p1y-cay, ez=p1z-caz;
                    float pd = sqrtf(fmaxf(ex*ex+ey*ey+ez*ez, EPS));
                    float de = fabsf(gd - pd);
                    ls1 += ((de<0.5f?1.f:0.f)+(de<1.f?1.f:0.f)+(de<2.f?1.f:0.f)+(de<4.f?1.f:0.f))*0.25f;
                    lc1 += 1.f;
                }
            }
        }
    }

    // ---- block-local reduction of 9 values (no global atomics) ----
    for (int o = 32; o > 0; o >>= 1) {
        a_ss += __shfl_down(a_ss, o, 64);  a_so += __shfl_down(a_so, o, 64);
        a_cs += __shfl_down(a_cs, o, 64);  a_co += __shfl_down(a_co, o, 64);
        a_rot += __shfl_down(a_rot, o, 64);
        ls0 += __shfl_down(ls0, o, 64);    lc0 += __shfl_down(lc0, o, 64);
        ls1 += __shfl_down(ls1, o, 64);    lc1 += __shfl_down(lc1, o, 64);
    }
    __shared__ float red[4][9];
    int wave = t >> 6, lane = t & 63;
    if (lane == 0) {
        red[wave][0]=a_ss; red[wave][1]=a_so; red[wave][2]=a_cs; red[wave][3]=a_co;
        red[wave][4]=a_rot; red[wave][5]=ls0; red[wave][6]=lc0; red[wave][7]=ls1; red[wave][8]=lc1;
    }
    __syncthreads();
    if (t == 0) {
        float v[9];
        #pragma unroll
        for (int k = 0; k < 9; k++)
            v[k] = red[0][k] + red[1][k] + red[2][k] + red[3][k];
        float* p = part + ((size_t)l * (N / IPB) + ib) * 8;
        p[0]=v[0]; p[1]=v[1]; p[2]=v[2]; p[3]=v[3]; p[4]=v[4];
        if (last) {
            out_lddt[i0] = v[5] / fmaxf(v[6], 1e-6f);
            out_lddt[i1] = v[7] / fmaxf(v[8], 1e-6f);
        }
    }
}

// ---------------- reduce: sum per-block partials -> scalars ----------------
__global__ __launch_bounds__(256) void reduce_kernel(
    const int* __restrict__ packed, const float* __restrict__ part,
    float* __restrict__ out, int L, int N)
{
    int t = threadIdx.x;
    int BPL = N / IPB;
    float ss[4]={0,0,0,0}, so[4]={0,0,0,0}, rt[4]={0,0,0,0};
    float cs=0.f, co=0.f;
    for (int b = t; b < BPL * L; b += 256) {
        int l = b / BPL;
        const float* p = part + (size_t)b * 8;
        ss[l] += p[0]; so[l] += p[1]; rt[l] += p[4];
        if (l == 0) { cs += p[2]; co += p[3]; }
    }
    float nr = 0.f;
    for (int i = t; i < N; i += 256)
        nr += ((packed[i] & 0xFFFF) != 0) ? 1.f : 0.f;

    __shared__ float red[4];
    int wave = t >> 6, lane = t & 63;
    float vals[11];
    vals[0]=cs; vals[1]=co; vals[2]=nr;
    for (int l = 0; l < L; l++) { vals[3+l]=ss[l]; vals[3+L+l]=so[l]; vals[3+2*L+l]=rt[l]; }
    float res[11];
    for (int k = 0; k < 3 + 3*L; k++) {
        float v = vals[k];
        for (int o = 32; o > 0; o >>= 1) v += __shfl_down(v, o, 64);
        __syncthreads();
        if (lane == 0) red[wave] = v;
        __syncthreads();
        res[k] = red[0] + red[1] + red[2] + red[3];
    }
    if (t == 0) {
        float csf = fmaxf(res[0], 1e-6f);
        float cof = fmaxf(res[1], 1e-6f);
        float nrm = fmaxf(res[2], 1e-6f);
        for (int l = 0; l < L; l++) {
            out[l]     = res[3+l] / csf / 10.f + res[3+L+l] / cof / 10.f;
            out[L + l] = res[3+2*L+l] / nrm;
        }
    }
}

extern "C" void kernel_launch(void* const* d_in, const int* in_sizes, int n_in,
                              void* d_out, int out_size, void* d_ws, size_t ws_size,
                              hipStream_t stream)
{
    const float* pred      = (const float*)d_in[0];
    const float* gt        = (const float*)d_in[1];
    const float* atom_mask = (const float*)d_in[2];
    const int*   batch     = (const int*)d_in[3];
    const int*   chain     = (const int*)d_in[4];

    int N = in_sizes[3];
    int A = in_sizes[2] / N;
    int L = in_sizes[0] / (N * A * 3);

    float* out = (float*)d_out;
    float* out_final = out + 2 * L;
    float* out_rot   = out_final + (size_t)N * N;
    float* out_lddt  = out_rot + N;

    float* ws = (float*)d_ws;
    float* Mc      = ws;                                  // L*N*12
    float* gtca    = Mc + (size_t)L * N * 12;             // N*3
    float* predca  = gtca + (size_t)N * 3;                // N*3
    float* part    = predca + (size_t)N * 3;              // (L*N/IPB)*8
    int*   packed  = (int*)(part + (size_t)L * (N / IPB) * 8);  // N

    int totalP = L * N;
    prep_kernel<<<(totalP + 255) / 256, 256, 0, stream>>>(
        pred, gt, atom_mask, batch, chain, Mc, packed, gtca, predca, L, N, A);

    dim3 grid(N / IPB, L);   // 384 x 2 = 768 blocks
    fape_kernel<<<grid, 256, 0, stream>>>(
        pred, gt, Mc, packed, gtca, predca, part,
        out_final, out_rot, out_lddt, L, N);

    reduce_kernel<<<1, 256, 0, stream>>>(packed, part, out, L, N);
}

// Round 8
// 92.722 us; speedup vs baseline: 1.7516x; 1.0567x over previous
//
#include <hip/hip_runtime.h>
#include <math.h>

#define EPS 1e-6f
#define IPB 2    // i per block

struct F3 { float x, y, z; };
__device__ inline F3 sub3(F3 a, F3 b){return {a.x-b.x,a.y-b.y,a.z-b.z};}
__device__ inline float dot3(F3 a, F3 b){return a.x*b.x+a.y*b.y+a.z*b.z;}
__device__ inline F3 scale3(F3 a,float s){return {a.x*s,a.y*s,a.z*s};}
__device__ inline F3 cross3(F3 a,F3 b){return {a.y*b.z-a.z*b.y, a.z*b.x-a.x*b.z, a.x*b.y-a.y*b.x};}
__device__ inline F3 norm3(F3 v){float s=dot3(v,v);float inv=1.f/sqrtf(fmaxf(s,EPS));return scale3(v,inv);}

__device__ inline void make_frame(const float* __restrict__ base, float R[9], F3& ca) {
    F3 n = {base[0], base[1], base[2]};
    ca   = {base[3], base[4], base[5]};
    F3 c = {base[6], base[7], base[8]};
    F3 e1 = norm3(sub3(c, ca));
    F3 v2 = sub3(n, ca);
    float d = dot3(e1, v2);
    F3 e2 = norm3({v2.x - d*e1.x, v2.y - d*e1.y, v2.z - d*e1.z});
    F3 e3 = cross3(e1, e2);
    R[0]=e1.x; R[1]=e1.y; R[2]=e1.z;
    R[3]=e2.x; R[4]=e2.y; R[5]=e2.z;
    R[6]=e3.x; R[7]=e3.y; R[8]=e3.z;
}

// ---------------- prep: fused M,c per (l,i); packed; CA arrays ----------------
__global__ __launch_bounds__(256) void prep_kernel(
    const float* __restrict__ pred, const float* __restrict__ gt,
    const float* __restrict__ atom_mask, const int* __restrict__ batch,
    const int* __restrict__ chain,
    float* __restrict__ Mc, int* __restrict__ packed,
    float* __restrict__ gtca, float* __restrict__ predca,
    int L, int N, int A)
{
    int idx = blockIdx.x * blockDim.x + threadIdx.x;
    if (idx >= L * N) return;
    int l = idx / N, i = idx - l * N;

    float Rg[9]; F3 cag;
    make_frame(gt + (size_t)i * A * 3, Rg, cag);
    float Rp[9]; F3 cap;
    make_frame(pred + ((size_t)l * N + i) * A * 3, Rp, cap);

    // |Rp^T(x-tp) - Rg^T(y-tg)| == |x - (M y + c)|, M = Rp Rg^T, c = tp - M tg
    float m[9];
    #pragma unroll
    for (int d = 0; d < 3; d++)
        #pragma unroll
        for (int e = 0; e < 3; e++)
            m[d*3+e] = Rp[0*3+d]*Rg[0*3+e] + Rp[1*3+d]*Rg[1*3+e] + Rp[2*3+d]*Rg[2*3+e];
    float c0 = cap.x - (m[0]*cag.x + m[1]*cag.y + m[2]*cag.z);
    float c1 = cap.y - (m[3]*cag.x + m[4]*cag.y + m[5]*cag.z);
    float c2 = cap.z - (m[6]*cag.x + m[7]*cag.y + m[8]*cag.z);

    float* o = Mc + (size_t)idx * 12;
    #pragma unroll
    for (int k = 0; k < 9; k++) o[k] = m[k];
    o[9] = c0; o[10] = c1; o[11] = c2;

    if (l == 0) {
        unsigned mm = 0;
        for (int a = 0; a < A; a++)
            if (atom_mask[(size_t)i * A + a] > 0.f) mm |= (1u << a);
        packed[i] = (int)(mm | ((unsigned)batch[i] << 16) | ((unsigned)chain[i] << 24));
        gtca[i*3] = cag.x; gtca[i*3+1] = cag.y; gtca[i*3+2] = cag.z;
    }
    if (l == L - 1) { predca[i*3] = cap.x; predca[i*3+1] = cap.y; predca[i*3+2] = cap.z; }
}

// ---------------- transpose to SoA: predT[l][c][j], gtT[c][j], c in [0,3A) ----
// Writes coalesced (lane=j); reads scattered but tiny total (~100K elements).
__global__ __launch_bounds__(256) void transpose_kernel(
    const float* __restrict__ pred, const float* __restrict__ gt,
    float* __restrict__ predT, float* __restrict__ gtT,
    int L, int N, int A)
{
    int j = blockIdx.x * 256 + threadIdx.x;
    if (j >= N) return;
    int c = blockIdx.y;          // [0, 3A)
    int z = blockIdx.z;          // [0, L] ; z==L -> gt
    int CA3 = 3 * A;
    if (z < L) predT[((size_t)z * CA3 + c) * N + j] = pred[((size_t)z * N + j) * CA3 + c];
    else       gtT[(size_t)c * N + j]               = gt[(size_t)j * CA3 + c];
}

// ---------------- fape: block = (l, i-pair), lanes stride j; SoA coalesced loads ----
__global__ __launch_bounds__(256) void fape_kernel(
    const float* __restrict__ predT, const float* __restrict__ gtT,
    const float* __restrict__ Mc, const int* __restrict__ packed,
    const float* __restrict__ gtca, const float* __restrict__ predca,
    float* __restrict__ part,
    float* __restrict__ out_final, float* __restrict__ out_rot,
    float* __restrict__ out_lddt,
    int L, int N)
{
    int t = threadIdx.x;
    int ib = blockIdx.x, l = blockIdx.y;
    int i0 = ib * IPB;
    int i1 = i0 + 1;
    bool last = (l == L - 1);

    // block-uniform -> scalar loads
    const float* __restrict__ mcp = Mc + ((size_t)l * N + i0) * 12;
    float A00=mcp[0],A01=mcp[1],A02=mcp[2],A10=mcp[3],A11=mcp[4],A12=mcp[5],
          A20=mcp[6],A21=mcp[7],A22=mcp[8],Ac0=mcp[9],Ac1=mcp[10],Ac2=mcp[11];
    float B00=mcp[12],B01=mcp[13],B02=mcp[14],B10=mcp[15],B11=mcp[16],B12=mcp[17],
          B20=mcp[18],B21=mcp[19],B22=mcp[20],Bc0=mcp[21],Bc1=mcp[22],Bc2=mcp[23];
    int pk0 = packed[i0], pk1 = packed[i1];
    int msk0 = pk0 & 0xFFFF, bat0 = (pk0 >> 16) & 0xFF, ch0 = (pk0 >> 24) & 0xFF;
    int msk1 = pk1 & 0xFFFF, bat1 = (pk1 >> 16) & 0xFF, ch1 = (pk1 >> 24) & 0xFF;

    float g0x=0,g0y=0,g0z=0,p0x=0,p0y=0,p0z=0;
    float g1x=0,g1y=0,g1z=0,p1x=0,p1y=0,p1z=0;
    if (last) {
        g0x=gtca[i0*3]; g0y=gtca[i0*3+1]; g0z=gtca[i0*3+2];
        p0x=predca[i0*3]; p0y=predca[i0*3+1]; p0z=predca[i0*3+2];
        g1x=gtca[i1*3]; g1y=gtca[i1*3+1]; g1z=gtca[i1*3+2];
        p1x=predca[i1*3]; p1y=predca[i1*3+1]; p1z=predca[i1*3+2];
    }

    const float* __restrict__ xT = predT + (size_t)l * 42 * N;   // [c][j]

    float a_ss=0.f, a_so=0.f, a_cs=0.f, a_co=0.f, a_rot=0.f;
    float ls0=0.f, lc0=0.f, ls1=0.f, lc1=0.f;

    for (int j = t; j < N; j += 256) {
        int pkj = packed[j];
        int mskj = pkj & 0xFFFF;
        int bj = (pkj >> 16) & 0xFF, cj = (pkj >> 24) & 0xFF;

        int mj0 = msk0 & mskj, mj1 = msk1 & mskj;
        bool pm0 = (bj == bat0) && (mj0 != 0);
        bool pm1 = (bj == bat1) && (mj1 != 0);
        float num0 = 0.f, num1 = 0.f;

        if (__any(pm0 || pm1)) {
            #pragma unroll
            for (int a = 0; a < 14; a++) {
                float Y0 = gtT[(a*3+0)*N + j];
                float Y1 = gtT[(a*3+1)*N + j];
                float Y2 = gtT[(a*3+2)*N + j];
                float X0 = xT[(a*3+0)*N + j];
                float X1 = xT[(a*3+1)*N + j];
                float X2 = xT[(a*3+2)*N + j];
                float d0 = X0 - (A00*Y0 + A01*Y1 + A02*Y2 + Ac0);
                float d1 = X1 - (A10*Y0 + A11*Y1 + A12*Y2 + Ac1);
                float d2 = X2 - (A20*Y0 + A21*Y1 + A22*Y2 + Ac2);
                num0 += (float)((mj0 >> a) & 1) * sqrtf(fmaxf(d0*d0+d1*d1+d2*d2, EPS));
                float e0 = X0 - (B00*Y0 + B01*Y1 + B02*Y2 + Bc0);
                float e1 = X1 - (B10*Y0 + B11*Y1 + B12*Y2 + Bc1);
                float e2 = X2 - (B20*Y0 + B21*Y1 + B22*Y2 + Bc2);
                num1 += (float)((mj1 >> a) & 1) * sqrtf(fmaxf(e0*e0+e1*e1+e2*e2, EPS));
            }
        }

        float fv0 = pm0 ? num0 / (float)__popc((unsigned)mj0) : 0.f;
        float fv1 = pm1 ? num1 / (float)__popc((unsigned)mj1) : 0.f;

        if (last) {
            out_final[(size_t)i0 * N + j] = fv0;   // coalesced
            out_final[(size_t)i1 * N + j] = fv1;
            if (j == i0) out_rot[i0] = fv0;
            if (j == i1) out_rot[i1] = fv1;
        }
        if (j == i0) a_rot += fv0;
        if (j == i1) a_rot += fv1;
        if (pm0) {
            float cl = fminf(fv0, 10.f);
            if (ch0 == cj) { a_ss += cl; a_cs += 1.f; } else { a_so += cl; a_co += 1.f; }
        }
        if (pm1) {
            float cl = fminf(fv1, 10.f);
            if (ch1 == cj) { a_ss += cl; a_cs += 1.f; } else { a_so += cl; a_co += 1.f; }
        }
        if (last) {
            // CA of row j from SoA (atom 1 = c 3..5), coalesced
            float cgx = gtT[3*N + j], cgy = gtT[4*N + j], cgz = gtT[5*N + j];
            float cax = xT[3*N + j],  cay = xT[4*N + j],  caz = xT[5*N + j];
            bool ok0 = (msk0 != 0) && (mskj != 0) && (j != i0);
            bool ok1 = (msk1 != 0) && (mskj != 0) && (j != i1);
            if (ok0) {
                float dx=g0x-cgx, dy=g0y-cgy, dz=g0z-cgz;
                float gd = sqrtf(fmaxf(dx*dx+dy*dy+dz*dz, EPS));
                if (gd < 15.f) {
                    float ex=p0x-cax, ey=p0y-cay, ez=p0z-caz;
                    float pd = sqrtf(fmaxf(ex*ex+ey*ey+ez*ez, EPS));
                    float de = fabsf(gd - pd);
                    ls0 += ((de<0.5f?1.f:0.f)+(de<1.f?1.f:0.f)+(de<2.f?1.f:0.f)+(de<4.f?1.f:0.f))*0.25f;
                    lc0 += 1.f;
                }
            }
            if (ok1) {
                float dx=g1x-cgx, dy=g1y-cgy, dz=g1z-cgz;
                float gd = sqrtf(fmaxf(dx*dx+dy*dy+dz*dz, EPS));
                if (gd < 15.f) {
                    float ex=p1x-cax, ey=p1y-cay, ez=p1z-caz;
                    float pd = sqrtf(fmaxf(ex*ex+ey*ey+ez*ez, EPS));
                    float de = fabsf(gd - pd);
                    ls1 += ((de<0.5f?1.f:0.f)+(de<1.f?1.f:0.f)+(de<2.f?1.f:0.f)+(de<4.f?1.f:0.f))*0.25f;
                    lc1 += 1.f;
                }
            }
        }
    }

    // ---- block-local reduction of 9 values (no global atomics) ----
    for (int o = 32; o > 0; o >>= 1) {
        a_ss += __shfl_down(a_ss, o, 64);  a_so += __shfl_down(a_so, o, 64);
        a_cs += __shfl_down(a_cs, o, 64);  a_co += __shfl_down(a_co, o, 64);
        a_rot += __shfl_down(a_rot, o, 64);
        ls0 += __shfl_down(ls0, o, 64);    lc0 += __shfl_down(lc0, o, 64);
        ls1 += __shfl_down(ls1, o, 64);    lc1 += __shfl_down(lc1, o, 64);
    }
    __shared__ float red[4][9];
    int wave = t >> 6, lane = t & 63;
    if (lane == 0) {
        red[wave][0]=a_ss; red[wave][1]=a_so; red[wave][2]=a_cs; red[wave][3]=a_co;
        red[wave][4]=a_rot; red[wave][5]=ls0; red[wave][6]=lc0; red[wave][7]=ls1; red[wave][8]=lc1;
    }
    __syncthreads();
    if (t == 0) {
        float v[9];
        #pragma unroll
        for (int k = 0; k < 9; k++)
            v[k] = red[0][k] + red[1][k] + red[2][k] + red[3][k];
        float* p = part + ((size_t)l * (N / IPB) + ib) * 8;
        p[0]=v[0]; p[1]=v[1]; p[2]=v[2]; p[3]=v[3]; p[4]=v[4];
        if (last) {
            out_lddt[i0] = v[5] / fmaxf(v[6], 1e-6f);
            out_lddt[i1] = v[7] / fmaxf(v[8], 1e-6f);
        }
    }
}

// ---------------- reduce: sum per-block partials -> scalars ----------------
__global__ __launch_bounds__(256) void reduce_kernel(
    const int* __restrict__ packed, const float* __restrict__ part,
    float* __restrict__ out, int L, int N)
{
    int t = threadIdx.x;
    int BPL = N / IPB;
    float ss[4]={0,0,0,0}, so[4]={0,0,0,0}, rt[4]={0,0,0,0};
    float cs=0.f, co=0.f;
    for (int b = t; b < BPL * L; b += 256) {
        int l = b / BPL;
        const float* p = part + (size_t)b * 8;
        ss[l] += p[0]; so[l] += p[1]; rt[l] += p[4];
        if (l == 0) { cs += p[2]; co += p[3]; }
    }
    float nr = 0.f;
    for (int i = t; i < N; i += 256)
        nr += ((packed[i] & 0xFFFF) != 0) ? 1.f : 0.f;

    __shared__ float red[4];
    int wave = t >> 6, lane = t & 63;
    float vals[11];
    vals[0]=cs; vals[1]=co; vals[2]=nr;
    for (int l = 0; l < L; l++) { vals[3+l]=ss[l]; vals[3+L+l]=so[l]; vals[3+2*L+l]=rt[l]; }
    float res[11];
    for (int k = 0; k < 3 + 3*L; k++) {
        float v = vals[k];
        for (int o = 32; o > 0; o >>= 1) v += __shfl_down(v, o, 64);
        __syncthreads();
        if (lane == 0) red[wave] = v;
        __syncthreads();
        res[k] = red[0] + red[1] + red[2] + red[3];
    }
    if (t == 0) {
        float csf = fmaxf(res[0], 1e-6f);
        float cof = fmaxf(res[1], 1e-6f);
        float nrm = fmaxf(res[2], 1e-6f);
        for (int l = 0; l < L; l++) {
            out[l]     = res[3+l] / csf / 10.f + res[3+L+l] / cof / 10.f;
            out[L + l] = res[3+2*L+l] / nrm;
        }
    }
}

extern "C" void kernel_launch(void* const* d_in, const int* in_sizes, int n_in,
                              void* d_out, int out_size, void* d_ws, size_t ws_size,
                              hipStream_t stream)
{
    const float* pred      = (const float*)d_in[0];
    const float* gt        = (const float*)d_in[1];
    const float* atom_mask = (const float*)d_in[2];
    const int*   batch     = (const int*)d_in[3];
    const int*   chain     = (const int*)d_in[4];

    int N = in_sizes[3];
    int A = in_sizes[2] / N;
    int L = in_sizes[0] / (N * A * 3);

    float* out = (float*)d_out;
    float* out_final = out + 2 * L;
    float* out_rot   = out_final + (size_t)N * N;
    float* out_lddt  = out_rot + N;

    float* ws = (float*)d_ws;
    float* Mc      = ws;                                  // L*N*12
    float* gtca    = Mc + (size_t)L * N * 12;             // N*3
    float* predca  = gtca + (size_t)N * 3;                // N*3
    float* part    = predca + (size_t)N * 3;              // (L*N/IPB)*8
    float* predT   = part + (size_t)L * (N / IPB) * 8;    // L*3A*N
    float* gtT     = predT + (size_t)L * 3 * A * N;       // 3A*N
    int*   packed  = (int*)(gtT + (size_t)3 * A * N);     // N

    int totalP = L * N;
    prep_kernel<<<(totalP + 255) / 256, 256, 0, stream>>>(
        pred, gt, atom_mask, batch, chain, Mc, packed, gtca, predca, L, N, A);

    dim3 tg((N + 255) / 256, 3 * A, L + 1);
    transpose_kernel<<<tg, 256, 0, stream>>>(pred, gt, predT, gtT, L, N, A);

    dim3 grid(N / IPB, L);   // 384 x 2 = 768 blocks
    fape_kernel<<<grid, 256, 0, stream>>>(
        predT, gtT, Mc, packed, gtca, predca, part,
        out_final, out_rot, out_lddt, L, N);

    reduce_kernel<<<1, 256, 0, stream>>>(packed, part, out, L, N);
}

// Round 9
// 89.090 us; speedup vs baseline: 1.8230x; 1.0408x over previous
//
#include <hip/hip_runtime.h>
#include <math.h>

#define EPS 1e-6f
#define IPB 2    // i per block

struct F3 { float x, y, z; };
__device__ inline F3 sub3(F3 a, F3 b){return {a.x-b.x,a.y-b.y,a.z-b.z};}
__device__ inline float dot3(F3 a, F3 b){return a.x*b.x+a.y*b.y+a.z*b.z;}
__device__ inline F3 scale3(F3 a,float s){return {a.x*s,a.y*s,a.z*s};}
__device__ inline F3 cross3(F3 a,F3 b){return {a.y*b.z-a.z*b.y, a.z*b.x-a.x*b.z, a.x*b.y-a.y*b.x};}
__device__ inline F3 norm3(F3 v){float s=dot3(v,v);float inv=1.f/sqrtf(fmaxf(s,EPS));return scale3(v,inv);}

__device__ inline void make_frame(const float* __restrict__ base, float R[9], F3& ca) {
    F3 n = {base[0], base[1], base[2]};
    ca   = {base[3], base[4], base[5]};
    F3 c = {base[6], base[7], base[8]};
    F3 e1 = norm3(sub3(c, ca));
    F3 v2 = sub3(n, ca);
    float d = dot3(e1, v2);
    F3 e2 = norm3({v2.x - d*e1.x, v2.y - d*e1.y, v2.z - d*e1.z});
    F3 e3 = cross3(e1, e2);
    R[0]=e1.x; R[1]=e1.y; R[2]=e1.z;
    R[3]=e2.x; R[4]=e2.y; R[5]=e2.z;
    R[6]=e3.x; R[7]=e3.y; R[8]=e3.z;
}

// ---------------- prep + transpose fused ----------------
// idx over (L+1)*A*N: transpose atom a of residue j (layer z; z==L -> gt) into
// float4 slabs predT4[(z*A + a)*N + j] = (x,y,z,0) / gtT4[a*N + j].
// idx < L*N additionally does frame/M,c/packed prep.
__global__ __launch_bounds__(256) void prep_all_kernel(
    const float* __restrict__ pred, const float* __restrict__ gt,
    const float* __restrict__ atom_mask, const int* __restrict__ batch,
    const int* __restrict__ chain,
    float* __restrict__ Mc, int* __restrict__ packed,
    float* __restrict__ gtca, float* __restrict__ predca,
    float4* __restrict__ predT4, float4* __restrict__ gtT4,
    int L, int N, int A)
{
    int idx = blockIdx.x * blockDim.x + threadIdx.x;

    // ---- transpose part ----
    int totalT = (L + 1) * A * N;
    if (idx < totalT) {
        int z = idx / (A * N);
        int r = idx - z * (A * N);
        int a = r / N;
        int j = r - a * N;
        if (z < L) {
            const float* s = pred + (((size_t)z * N + j) * A + a) * 3;
            predT4[((size_t)z * A + a) * N + j] = make_float4(s[0], s[1], s[2], 0.f);
        } else {
            const float* s = gt + ((size_t)j * A + a) * 3;
            gtT4[(size_t)a * N + j] = make_float4(s[0], s[1], s[2], 0.f);
        }
    }

    // ---- prep part ----
    if (idx >= L * N) return;
    int l = idx / N, i = idx - l * N;

    float Rg[9]; F3 cag;
    make_frame(gt + (size_t)i * A * 3, Rg, cag);
    float Rp[9]; F3 cap;
    make_frame(pred + ((size_t)l * N + i) * A * 3, Rp, cap);

    // |Rp^T(x-tp) - Rg^T(y-tg)| == |x - (M y + c)|, M = Rp Rg^T, c = tp - M tg
    float m[9];
    #pragma unroll
    for (int d = 0; d < 3; d++)
        #pragma unroll
        for (int e = 0; e < 3; e++)
            m[d*3+e] = Rp[0*3+d]*Rg[0*3+e] + Rp[1*3+d]*Rg[1*3+e] + Rp[2*3+d]*Rg[2*3+e];
    float c0 = cap.x - (m[0]*cag.x + m[1]*cag.y + m[2]*cag.z);
    float c1 = cap.y - (m[3]*cag.x + m[4]*cag.y + m[5]*cag.z);
    float c2 = cap.z - (m[6]*cag.x + m[7]*cag.y + m[8]*cag.z);

    float* o = Mc + (size_t)idx * 12;
    #pragma unroll
    for (int k = 0; k < 9; k++) o[k] = m[k];
    o[9] = c0; o[10] = c1; o[11] = c2;

    if (l == 0) {
        unsigned mm = 0;
        for (int a = 0; a < A; a++)
            if (atom_mask[(size_t)i * A + a] > 0.f) mm |= (1u << a);
        packed[i] = (int)(mm | ((unsigned)batch[i] << 16) | ((unsigned)chain[i] << 24));
        gtca[i*3] = cag.x; gtca[i*3+1] = cag.y; gtca[i*3+2] = cag.z;
    }
    if (l == L - 1) { predca[i*3] = cap.x; predca[i*3+1] = cap.y; predca[i*3+2] = cap.z; }
}

// ---------------- fape: block = (l, i-pair), lanes stride j; float4 SoA loads ----
__global__ __launch_bounds__(256) void fape_kernel(
    const float4* __restrict__ predT4, const float4* __restrict__ gtT4,
    const float* __restrict__ Mc, const int* __restrict__ packed,
    const float* __restrict__ gtca, const float* __restrict__ predca,
    float* __restrict__ part,
    float* __restrict__ out_final, float* __restrict__ out_rot,
    float* __restrict__ out_lddt,
    int L, int N)
{
    int t = threadIdx.x;
    int ib = blockIdx.x, l = blockIdx.y;
    int i0 = ib * IPB;
    int i1 = i0 + 1;
    bool last = (l == L - 1);

    // block-uniform -> scalar loads
    const float* __restrict__ mcp = Mc + ((size_t)l * N + i0) * 12;
    float A00=mcp[0],A01=mcp[1],A02=mcp[2],A10=mcp[3],A11=mcp[4],A12=mcp[5],
          A20=mcp[6],A21=mcp[7],A22=mcp[8],Ac0=mcp[9],Ac1=mcp[10],Ac2=mcp[11];
    float B00=mcp[12],B01=mcp[13],B02=mcp[14],B10=mcp[15],B11=mcp[16],B12=mcp[17],
          B20=mcp[18],B21=mcp[19],B22=mcp[20],Bc0=mcp[21],Bc1=mcp[22],Bc2=mcp[23];
    int pk0 = packed[i0], pk1 = packed[i1];
    int msk0 = pk0 & 0xFFFF, bat0 = (pk0 >> 16) & 0xFF, ch0 = (pk0 >> 24) & 0xFF;
    int msk1 = pk1 & 0xFFFF, bat1 = (pk1 >> 16) & 0xFF, ch1 = (pk1 >> 24) & 0xFF;

    float g0x=0,g0y=0,g0z=0,p0x=0,p0y=0,p0z=0;
    float g1x=0,g1y=0,g1z=0,p1x=0,p1y=0,p1z=0;
    if (last) {
        g0x=gtca[i0*3]; g0y=gtca[i0*3+1]; g0z=gtca[i0*3+2];
        p0x=predca[i0*3]; p0y=predca[i0*3+1]; p0z=predca[i0*3+2];
        g1x=gtca[i1*3]; g1y=gtca[i1*3+1]; g1z=gtca[i1*3+2];
        p1x=predca[i1*3]; p1y=predca[i1*3+1]; p1z=predca[i1*3+2];
    }

    const float4* __restrict__ xT4 = predT4 + (size_t)l * 14 * N;   // [a][j]

    float a_ss=0.f, a_so=0.f, a_cs=0.f, a_co=0.f, a_rot=0.f;
    float ls0=0.f, lc0=0.f, ls1=0.f, lc1=0.f;

    for (int j = t; j < N; j += 256) {
        int pkj = packed[j];
        int mskj = pkj & 0xFFFF;
        int bj = (pkj >> 16) & 0xFF, cj = (pkj >> 24) & 0xFF;

        int mj0 = msk0 & mskj, mj1 = msk1 & mskj;
        bool pm0 = (bj == bat0) && (mj0 != 0);
        bool pm1 = (bj == bat1) && (mj1 != 0);
        float num0 = 0.f, num1 = 0.f;

        if (__any(pm0 || pm1)) {
            #pragma unroll
            for (int a = 0; a < 14; a++) {
                float4 Y = gtT4[(size_t)a * N + j];   // coalesced dwordx4
                float4 X = xT4[(size_t)a * N + j];
                float d0 = X.x - (A00*Y.x + A01*Y.y + A02*Y.z + Ac0);
                float d1 = X.y - (A10*Y.x + A11*Y.y + A12*Y.z + Ac1);
                float d2 = X.z - (A20*Y.x + A21*Y.y + A22*Y.z + Ac2);
                num0 += (float)((mj0 >> a) & 1) * sqrtf(fmaxf(d0*d0+d1*d1+d2*d2, EPS));
                float e0 = X.x - (B00*Y.x + B01*Y.y + B02*Y.z + Bc0);
                float e1 = X.y - (B10*Y.x + B11*Y.y + B12*Y.z + Bc1);
                float e2 = X.z - (B20*Y.x + B21*Y.y + B22*Y.z + Bc2);
                num1 += (float)((mj1 >> a) & 1) * sqrtf(fmaxf(e0*e0+e1*e1+e2*e2, EPS));
            }
        }

        float fv0 = pm0 ? num0 / (float)__popc((unsigned)mj0) : 0.f;
        float fv1 = pm1 ? num1 / (float)__popc((unsigned)mj1) : 0.f;

        if (last) {
            out_final[(size_t)i0 * N + j] = fv0;   // coalesced
            out_final[(size_t)i1 * N + j] = fv1;
            if (j == i0) out_rot[i0] = fv0;
            if (j == i1) out_rot[i1] = fv1;
        }
        if (j == i0) a_rot += fv0;
        if (j == i1) a_rot += fv1;
        if (pm0) {
            float cl = fminf(fv0, 10.f);
            if (ch0 == cj) { a_ss += cl; a_cs += 1.f; } else { a_so += cl; a_co += 1.f; }
        }
        if (pm1) {
            float cl = fminf(fv1, 10.f);
            if (ch1 == cj) { a_ss += cl; a_cs += 1.f; } else { a_so += cl; a_co += 1.f; }
        }
        if (last) {
            float4 CG = gtT4[(size_t)1 * N + j];   // CA of row j (atom 1)
            float4 CP = xT4[(size_t)1 * N + j];
            bool ok0 = (msk0 != 0) && (mskj != 0) && (j != i0);
            bool ok1 = (msk1 != 0) && (mskj != 0) && (j != i1);
            if (ok0) {
                float dx=g0x-CG.x, dy=g0y-CG.y, dz=g0z-CG.z;
                float gd = sqrtf(fmaxf(dx*dx+dy*dy+dz*dz, EPS));
                if (gd < 15.f) {
                    float ex=p0x-CP.x, ey=p0y-CP.y, ez=p0z-CP.z;
                    float pd = sqrtf(fmaxf(ex*ex+ey*ey+ez*ez, EPS));
                    float de = fabsf(gd - pd);
                    ls0 += ((de<0.5f?1.f:0.f)+(de<1.f?1.f:0.f)+(de<2.f?1.f:0.f)+(de<4.f?1.f:0.f))*0.25f;
                    lc0 += 1.f;
                }
            }
            if (ok1) {
                float dx=g1x-CG.x, dy=g1y-CG.y, dz=g1z-CG.z;
                float gd = sqrtf(fmaxf(dx*dx+dy*dy+dz*dz, EPS));
                if (gd < 15.f) {
                    float ex=p1x-CP.x, ey=p1y-CP.y, ez=p1z-CP.z;
                    float pd = sqrtf(fmaxf(ex*ex+ey*ey+ez*ez, EPS));
                    float de = fabsf(gd - pd);
                    ls1 += ((de<0.5f?1.f:0.f)+(de<1.f?1.f:0.f)+(de<2.f?1.f:0.f)+(de<4.f?1.f:0.f))*0.25f;
                    lc1 += 1.f;
                }
            }
        }
    }

    // ---- block-local reduction of 9 values (no global atomics) ----
    for (int o = 32; o > 0; o >>= 1) {
        a_ss += __shfl_down(a_ss, o, 64);  a_so += __shfl_down(a_so, o, 64);
        a_cs += __shfl_down(a_cs, o, 64);  a_co += __shfl_down(a_co, o, 64);
        a_rot += __shfl_down(a_rot, o, 64);
        ls0 += __shfl_down(ls0, o, 64);    lc0 += __shfl_down(lc0, o, 64);
        ls1 += __shfl_down(ls1, o, 64);    lc1 += __shfl_down(lc1, o, 64);
    }
    __shared__ float red[4][9];
    int wave = t >> 6, lane = t & 63;
    if (lane == 0) {
        red[wave][0]=a_ss; red[wave][1]=a_so; red[wave][2]=a_cs; red[wave][3]=a_co;
        red[wave][4]=a_rot; red[wave][5]=ls0; red[wave][6]=lc0; red[wave][7]=ls1; red[wave][8]=lc1;
    }
    __syncthreads();
    if (t == 0) {
        float v[9];
        #pragma unroll
        for (int k = 0; k < 9; k++)
            v[k] = red[0][k] + red[1][k] + red[2][k] + red[3][k];
        float* p = part + ((size_t)l * (N / IPB) + ib) * 8;
        p[0]=v[0]; p[1]=v[1]; p[2]=v[2]; p[3]=v[3]; p[4]=v[4];
        if (last) {
            out_lddt[i0] = v[5] / fmaxf(v[6], 1e-6f);
            out_lddt[i1] = v[7] / fmaxf(v[8], 1e-6f);
        }
    }
}

// ---------------- reduce: sum per-block partials -> scalars ----------------
__global__ __launch_bounds__(256) void reduce_kernel(
    const int* __restrict__ packed, const float* __restrict__ part,
    float* __restrict__ out, int L, int N)
{
    int t = threadIdx.x;
    int BPL = N / IPB;
    float ss[4]={0,0,0,0}, so[4]={0,0,0,0}, rt[4]={0,0,0,0};
    float cs=0.f, co=0.f;
    for (int b = t; b < BPL * L; b += 256) {
        int l = b / BPL;
        const float* p = part + (size_t)b * 8;
        ss[l] += p[0]; so[l] += p[1]; rt[l] += p[4];
        if (l == 0) { cs += p[2]; co += p[3]; }
    }
    float nr = 0.f;
    for (int i = t; i < N; i += 256)
        nr += ((packed[i] & 0xFFFF) != 0) ? 1.f : 0.f;

    __shared__ float red[4];
    int wave = t >> 6, lane = t & 63;
    float vals[11];
    vals[0]=cs; vals[1]=co; vals[2]=nr;
    for (int l = 0; l < L; l++) { vals[3+l]=ss[l]; vals[3+L+l]=so[l]; vals[3+2*L+l]=rt[l]; }
    float res[11];
    for (int k = 0; k < 3 + 3*L; k++) {
        float v = vals[k];
        for (int o = 32; o > 0; o >>= 1) v += __shfl_down(v, o, 64);
        __syncthreads();
        if (lane == 0) red[wave] = v;
        __syncthreads();
        res[k] = red[0] + red[1] + red[2] + red[3];
    }
    if (t == 0) {
        float csf = fmaxf(res[0], 1e-6f);
        float cof = fmaxf(res[1], 1e-6f);
        float nrm = fmaxf(res[2], 1e-6f);
        for (int l = 0; l < L; l++) {
            out[l]     = res[3+l] / csf / 10.f + res[3+L+l] / cof / 10.f;
            out[L + l] = res[3+2*L+l] / nrm;
        }
    }
}

extern "C" void kernel_launch(void* const* d_in, const int* in_sizes, int n_in,
                              void* d_out, int out_size, void* d_ws, size_t ws_size,
                              hipStream_t stream)
{
    const float* pred      = (const float*)d_in[0];
    const float* gt        = (const float*)d_in[1];
    const float* atom_mask = (const float*)d_in[2];
    const int*   batch     = (const int*)d_in[3];
    const int*   chain     = (const int*)d_in[4];

    int N = in_sizes[3];
    int A = in_sizes[2] / N;
    int L = in_sizes[0] / (N * A * 3);

    float* out = (float*)d_out;
    float* out_final = out + 2 * L;
    float* out_rot   = out_final + (size_t)N * N;
    float* out_lddt  = out_rot + N;

    float* ws = (float*)d_ws;
    float* Mc      = ws;                                  // L*N*12
    float* gtca    = Mc + (size_t)L * N * 12;             // N*3
    float* predca  = gtca + (size_t)N * 3;                // N*3
    float* part    = predca + (size_t)N * 3;              // (L*N/IPB)*8
    float4* predT4 = (float4*)(part + (size_t)L * (N / IPB) * 8);  // L*A*N float4
    float4* gtT4   = predT4 + (size_t)L * A * N;          // A*N float4
    int*   packed  = (int*)(gtT4 + (size_t)A * N);        // N

    int totalT = (L + 1) * A * N;
    prep_all_kernel<<<(totalT + 255) / 256, 256, 0, stream>>>(
        pred, gt, atom_mask, batch, chain,
        Mc, packed, gtca, predca, predT4, gtT4, L, N, A);

    dim3 grid(N / IPB, L);   // 384 x 2 = 768 blocks
    fape_kernel<<<grid, 256, 0, stream>>>(
        predT4, gtT4, Mc, packed, gtca, predca, part,
        out_final, out_rot, out_lddt, L, N);

    reduce_kernel<<<1, 256, 0, stream>>>(packed, part, out, L, N);
}